// Round 4
// baseline (511.652 us; speedup 1.0000x reference)
//
#include <hip/hip_runtime.h>

#define B_ 32
#define T_ 12
#define F_ 4
#define L_ 1024
#define H_ 64
#define NROWS 1920   // 1536 x rows + 6*64 bias rows
#define NCH 256      // chunks (blocks); 4 links per chunk

typedef _Float16 f16x8 __attribute__((ext_vector_type(8)));
typedef float f32x4 __attribute__((ext_vector_type(4)));

// XCD-chunked swizzle: XCD x owns chunks [32x, 32x+32) = links [128x, 128x+128)
__device__ __forceinline__ int chunk_of_block(int bid) {
    return ((bid & 7) << 5) + (bid >> 3);
}

// ---------------------------------------------------------------------------
// Prep: transpose x [1536 rows][L] and 6 bias arrays [64 rows][L] into
// params[l][NROWS], zero the flags.
// ---------------------------------------------------------------------------
__global__ __launch_bounds__(256) void prep(
    const float* __restrict__ x,
    const float* __restrict__ b_rh, const float* __restrict__ b_ri,
    const float* __restrict__ b_uh, const float* __restrict__ b_ui,
    const float* __restrict__ b_nh, const float* __restrict__ b_ni,
    float* __restrict__ params, int* __restrict__ flags)
{
    const int tid = threadIdx.x;
    const int rt  = blockIdx.x >> 4;   // 30 row tiles
    const int lt  = blockIdx.x & 15;   // 16 link tiles
    __shared__ float lds[64][65];

    if (blockIdx.x == 0 && tid < NCH) flags[tid] = 0;

    #pragma unroll
    for (int i = 0; i < 16; ++i) {
        const int e  = i * 256 + tid;
        const int rl = e >> 6, ll = e & 63;
        const int r  = rt * 64 + rl, l = lt * 64 + ll;
        float v;
        if (r < 1536) {
            v = x[(size_t)r * L_ + l];
        } else {
            const int rb = r - 1536;
            const int g  = rb >> 6;
            const float* bp = (g == 0) ? b_rh : (g == 1) ? b_ri : (g == 2) ? b_uh
                            : (g == 3) ? b_ui : (g == 4) ? b_nh : b_ni;
            v = bp[(size_t)(rb & 63) * L_ + l];
        }
        lds[rl][ll] = v;
    }
    __syncthreads();
    #pragma unroll
    for (int i = 0; i < 16; ++i) {
        const int e  = i * 256 + tid;
        const int ll = e >> 6, rl = e & 63;
        params[(size_t)(lt * 64 + ll) * NROWS + rt * 64 + rl] = lds[rl][ll];
    }
}

// LDS h buffer: [parity][link 0..3][b 0..31][k 0..63] fp16, XOR-swizzled rows
__device__ __forceinline__ int h_byte(int p, int w, int b, int k) {
    int byte = ((((p * 4 + w) * 32 + b) * 64) + k) * 2;
    return byte ^ ((b & 7) << 4);
}

// ---------------------------------------------------------------------------
// Persistent GRU: 256 blocks (1/CU), wave w of block owns link 4c+w for all
// T steps. Weights in registers; interior neighbors via LDS; chunk-edge h via
// global fp16 halos + per-chunk flags (skew <= 1 step, ping-pong parity).
// gh layout: [parity][chunk][side][b][k] fp16 (side 0 = left edge link 4c,
// side 1 = right edge link 4c+3).
// ---------------------------------------------------------------------------
__global__ __launch_bounds__(256, 1) void gru_persist(
    const float* __restrict__ w_rh, const float* __restrict__ w_uh,
    const float* __restrict__ w_nh,
    const float* __restrict__ w_ri, const float* __restrict__ w_ui,
    const float* __restrict__ w_ni,
    const float* __restrict__ att,  const float* __restrict__ params,
    const float* __restrict__ w_fc, const float* __restrict__ b_fc,
    _Float16* __restrict__ gh, int* __restrict__ flags,
    float* __restrict__ out)
{
    const int c    = chunk_of_block(blockIdx.x);
    const int tid  = threadIdx.x;
    const int w    = tid >> 6, lane = tid & 63;
    const int n    = lane & 15, kq = lane >> 4;
    const int l    = c * 4 + w;

    __shared__ __align__(16) _Float16 hbuf[2 * 4 * 32 * 64];  // 32 KB
    __shared__ __align__(16) float    xs[4][1536];            // 24 KB

    // ---- stage this link's x (+nothing else) into LDS, coalesced
    const float* prow = params + (size_t)l * NROWS;
    {
        const float4* src = (const float4*)prow;
        float4* dst = (float4*)xs[w];
        #pragma unroll
        for (int i = 0; i < 6; ++i) dst[lane + i * 64] = src[lane + i * 64];
    }

    // ---- per-lane persistent constants
    f16x8 bw[3][4][2];   // B fragments [gate][ntile][ks]
    {
        const float* wh[3] = { w_rh, w_uh, w_nh };
        #pragma unroll
        for (int g = 0; g < 3; ++g)
            #pragma unroll
            for (int nt = 0; nt < 4; ++nt)
                #pragma unroll
                for (int ks = 0; ks < 2; ++ks) {
                    f16x8 v;
                    #pragma unroll
                    for (int j = 0; j < 8; ++j)
                        v[j] = (_Float16)wh[g][(size_t)l * 4096
                                 + (size_t)(ks * 32 + kq * 8 + j) * 64 + nt * 16 + n];
                    bw[g][nt][ks] = v;
                }
    }
    float wxv[3][4][4];  // [gate][f][ntile]
    {
        const float* wxp[3] = { w_ri, w_ui, w_ni };
        #pragma unroll
        for (int g = 0; g < 3; ++g)
            #pragma unroll
            for (int f = 0; f < F_; ++f)
                #pragma unroll
                for (int nt = 0; nt < 4; ++nt)
                    wxv[g][f][nt] = wxp[g][(size_t)l * 256 + f * 64 + nt * 16 + n];
    }
    float brv[4], bzv[4], bnhv[4], bniv[4], wfcv[4];
    #pragma unroll
    for (int nt = 0; nt < 4; ++nt) {
        const int ko = nt * 16 + n;
        brv[nt]  = prow[1536 + 0 * 64 + ko] + prow[1536 + 1 * 64 + ko];
        bzv[nt]  = prow[1536 + 2 * 64 + ko] + prow[1536 + 3 * 64 + ko];
        bnhv[nt] = prow[1536 + 4 * 64 + ko];
        bniv[nt] = prow[1536 + 5 * 64 + ko];
        wfcv[nt] = w_fc[(size_t)l * H_ + ko];
    }
    const float a_c = att[(size_t)l * L_ + l];
    const float a_l = (l > 0)      ? att[(size_t)l * L_ + l - 1] : 0.0f;
    const float a_r = (l < L_ - 1) ? att[(size_t)l * L_ + l + 1] : 0.0f;

    __syncthreads();   // xs ready

    float hv[2][4][4] = {};   // [mt][nt][r], f32 running hidden state

    #pragma unroll 1
    for (int t = 0; t < T_; ++t) {
        f32x4 acc[3][2][4] = {};   // [gate][mt][nt]
        if (t > 0) {
            if (c > 0 && tid == 0)
                while (__hip_atomic_load(&flags[c - 1], __ATOMIC_ACQUIRE,
                                         __HIP_MEMORY_SCOPE_AGENT) < t)
                    __builtin_amdgcn_s_sleep(2);
            if (c < NCH - 1 && tid == 255)
                while (__hip_atomic_load(&flags[c + 1], __ATOMIC_ACQUIRE,
                                         __HIP_MEMORY_SCOPE_AGENT) < t)
                    __builtin_amdgcn_s_sleep(2);
            __syncthreads();
            __threadfence();   // acquire: invalidate stale halo lines

            const int p = (t - 1) & 1;
            const char* hb = (const char*)hbuf;
            f16x8 af[2][2];
            #pragma unroll
            for (int mt = 0; mt < 2; ++mt) {
                #pragma unroll
                for (int ks = 0; ks < 2; ++ks) {
                    const int b  = mt * 16 + n;
                    const int k0 = ks * 32 + kq * 8;
                    const f16x8 hs = *(const f16x8*)(hb + h_byte(p, w, b, k0));
                    f16x8 hl, hr;
                    if (w > 0)            hl = *(const f16x8*)(hb + h_byte(p, w - 1, b, k0));
                    else if (c > 0)       hl = *(const f16x8*)(gh +
                        ((((size_t)p * NCH + (c - 1)) * 2 + 1) * 32 + b) * 64 + k0);
                    else                  hl = hs;   // a_l == 0
                    if (w < 3)            hr = *(const f16x8*)(hb + h_byte(p, w + 1, b, k0));
                    else if (c < NCH - 1) hr = *(const f16x8*)(gh +
                        ((((size_t)p * NCH + (c + 1)) * 2 + 0) * 32 + b) * 64 + k0);
                    else                  hr = hs;   // a_r == 0
                    f16x8 a;
                    #pragma unroll
                    for (int j = 0; j < 8; ++j)
                        a[j] = (_Float16)(a_c * (float)hs[j] + a_l * (float)hl[j]
                                        + a_r * (float)hr[j]);
                    af[mt][ks] = a;
                }
            }
            #pragma unroll
            for (int g = 0; g < 3; ++g)
                #pragma unroll
                for (int nt = 0; nt < 4; ++nt)
                    #pragma unroll
                    for (int ks = 0; ks < 2; ++ks)
                        #pragma unroll
                        for (int mt = 0; mt < 2; ++mt)
                            acc[g][mt][nt] = __builtin_amdgcn_mfma_f32_16x16x32_f16(
                                af[mt][ks], bw[g][nt][ks], acc[g][mt][nt], 0, 0, 0);
        }

        // ---- epilogue (f32)
        #pragma unroll
        for (int mt = 0; mt < 2; ++mt) {
            #pragma unroll
            for (int r = 0; r < 4; ++r) {
                const int b = mt * 16 + kq * 4 + r;
                const float4 xb = *(const float4*)&xs[w][b * 48 + t * 4];
                #pragma unroll
                for (int nt = 0; nt < 4; ++nt) {
                    const float xr = xb.x*wxv[0][0][nt] + xb.y*wxv[0][1][nt]
                                   + xb.z*wxv[0][2][nt] + xb.w*wxv[0][3][nt];
                    const float xz = xb.x*wxv[1][0][nt] + xb.y*wxv[1][1][nt]
                                   + xb.z*wxv[1][2][nt] + xb.w*wxv[1][3][nt];
                    const float xn = xb.x*wxv[2][0][nt] + xb.y*wxv[2][1][nt]
                                   + xb.z*wxv[2][2][nt] + xb.w*wxv[2][3][nt];
                    const float pre_r = acc[0][mt][nt][r] + brv[nt] + xr;
                    const float pre_z = acc[1][mt][nt][r] + bzv[nt] + xz;
                    const float rg = 1.0f / (1.0f + __expf(-pre_r));
                    const float zg = 1.0f / (1.0f + __expf(-pre_z));
                    float npre = xn + bniv[nt] + rg * (acc[2][mt][nt][r] + bnhv[nt]);
                    npre = fminf(fmaxf(npre, -15.0f), 15.0f);
                    const float e2 = __expf(2.0f * npre);
                    const float nn = (e2 - 1.0f) / (e2 + 1.0f);
                    hv[mt][nt][r] = (1.0f - zg) * nn + zg * hv[mt][nt][r];
                }
            }
        }

        if (t < T_ - 1) {
            const int q = t & 1;
            char* hb = (char*)hbuf;
            #pragma unroll
            for (int mt = 0; mt < 2; ++mt)
                #pragma unroll
                for (int nt = 0; nt < 4; ++nt)
                    #pragma unroll
                    for (int r = 0; r < 4; ++r) {
                        const int b = mt * 16 + kq * 4 + r;
                        const int k = nt * 16 + n;
                        *(_Float16*)(hb + h_byte(q, w, b, k)) = (_Float16)hv[mt][nt][r];
                    }
            if (w == 0 || w == 3) {
                const int side = (w == 0) ? 0 : 1;
                _Float16* ge = gh + (((size_t)q * NCH + c) * 2 + side) * 2048;
                #pragma unroll
                for (int mt = 0; mt < 2; ++mt)
                    #pragma unroll
                    for (int nt = 0; nt < 4; ++nt)
                        #pragma unroll
                        for (int r = 0; r < 4; ++r) {
                            const int b = mt * 16 + kq * 4 + r;
                            ge[b * 64 + nt * 16 + n] = (_Float16)hv[mt][nt][r];
                        }
            }
            __syncthreads();   // all LDS + edge global stores drained
            if (tid == 0) {
                __threadfence();   // release: push edge h to device scope
                __hip_atomic_store(&flags[c], t + 1, __ATOMIC_RELEASE,
                                   __HIP_MEMORY_SCOPE_AGENT);
            }
        } else {
            // FC head: out[b][0][l] = sum_k h[b][k]*w_fc[l][k] + b_fc[l]
            #pragma unroll
            for (int mt = 0; mt < 2; ++mt)
                #pragma unroll
                for (int r = 0; r < 4; ++r) {
                    float s = hv[mt][0][r] * wfcv[0] + hv[mt][1][r] * wfcv[1]
                            + hv[mt][2][r] * wfcv[2] + hv[mt][3][r] * wfcv[3];
                    s += __shfl_xor(s, 1, 64);
                    s += __shfl_xor(s, 2, 64);
                    s += __shfl_xor(s, 4, 64);
                    s += __shfl_xor(s, 8, 64);
                    if (n == 0)
                        out[(size_t)(mt * 16 + kq * 4 + r) * L_ + l] = s + b_fc[l];
                }
        }
    }
}

extern "C" void kernel_launch(void* const* d_in, const int* in_sizes, int n_in,
                              void* d_out, int out_size, void* d_ws, size_t ws_size,
                              hipStream_t stream) {
    const float* x    = (const float*)d_in[0];
    const float* att  = (const float*)d_in[1];
    const float* w_rh = (const float*)d_in[2];
    const float* b_rh = (const float*)d_in[3];
    const float* w_ri = (const float*)d_in[4];
    const float* b_ri = (const float*)d_in[5];
    const float* w_uh = (const float*)d_in[6];
    const float* b_uh = (const float*)d_in[7];
    const float* w_ui = (const float*)d_in[8];
    const float* b_ui = (const float*)d_in[9];
    const float* w_nh = (const float*)d_in[10];
    const float* b_nh = (const float*)d_in[11];
    const float* w_ni = (const float*)d_in[12];
    const float* b_ni = (const float*)d_in[13];
    const float* w_fc = (const float*)d_in[14];
    const float* b_fc = (const float*)d_in[15];
    float* out = (float*)d_out;

    char* ws = (char*)d_ws;
    float*    params = (float*)ws;                    // 7.9 MB
    _Float16* gh     = (_Float16*)(ws + (8u << 20));  // 4 MB edge halos
    int*      flags  = (int*)(ws + (13u << 20));      // 1 KB

    prep<<<480, 256, 0, stream>>>(x, b_rh, b_ri, b_uh, b_ui, b_nh, b_ni,
                                  params, flags);

    void* args[] = {
        (void*)&w_rh, (void*)&w_uh, (void*)&w_nh,
        (void*)&w_ri, (void*)&w_ui, (void*)&w_ni,
        (void*)&att,  (void*)&params, (void*)&w_fc, (void*)&b_fc,
        (void*)&gh,   (void*)&flags,  (void*)&out,
    };
    hipError_t e = hipLaunchCooperativeKernel((const void*)gru_persist,
                                              dim3(NCH), dim3(256), args, 0, stream);
    if (e != hipSuccess) {
        // 256 blocks at 1 block/CU on 256 CUs: de-facto co-resident.
        gru_persist<<<NCH, 256, 0, stream>>>(w_rh, w_uh, w_nh, w_ri, w_ui, w_ni,
                                             att, params, w_fc, b_fc,
                                             gh, flags, out);
    }
}

// Round 5
// 225.665 us; speedup vs baseline: 2.2673x; 2.2673x over previous
//
#include <hip/hip_runtime.h>

#define B_ 32
#define T_ 12
#define F_ 4
#define L_ 1024
#define H_ 64
#define NROWS 1920   // 1536 x rows + 6*64 bias rows
#define NCH 256      // chunks (blocks); 4 links per chunk

typedef _Float16 f16x8 __attribute__((ext_vector_type(8)));
typedef float f32x4 __attribute__((ext_vector_type(4)));
typedef unsigned long long u64;

// XCD-chunked swizzle: XCD x owns chunks [32x, 32x+32) = links [128x, 128x+128)
__device__ __forceinline__ int chunk_of_block(int bid) {
    return ((bid & 7) << 5) + (bid >> 3);
}

// ---------------------------------------------------------------------------
// Prep: transpose x [1536 rows][L] and 6 bias arrays [64 rows][L] into
// params[l][NROWS], zero the flags.
// ---------------------------------------------------------------------------
__global__ __launch_bounds__(256) void prep(
    const float* __restrict__ x,
    const float* __restrict__ b_rh, const float* __restrict__ b_ri,
    const float* __restrict__ b_uh, const float* __restrict__ b_ui,
    const float* __restrict__ b_nh, const float* __restrict__ b_ni,
    float* __restrict__ params, int* __restrict__ flags)
{
    const int tid = threadIdx.x;
    const int rt  = blockIdx.x >> 4;   // 30 row tiles
    const int lt  = blockIdx.x & 15;   // 16 link tiles
    __shared__ float lds[64][65];

    if (blockIdx.x == 0 && tid < NCH)
        __hip_atomic_store(&flags[tid], 0, __ATOMIC_RELAXED, __HIP_MEMORY_SCOPE_AGENT);

    #pragma unroll
    for (int i = 0; i < 16; ++i) {
        const int e  = i * 256 + tid;
        const int rl = e >> 6, ll = e & 63;
        const int r  = rt * 64 + rl, l = lt * 64 + ll;
        float v;
        if (r < 1536) {
            v = x[(size_t)r * L_ + l];
        } else {
            const int rb = r - 1536;
            const int g  = rb >> 6;
            const float* bp = (g == 0) ? b_rh : (g == 1) ? b_ri : (g == 2) ? b_uh
                            : (g == 3) ? b_ui : (g == 4) ? b_nh : b_ni;
            v = bp[(size_t)(rb & 63) * L_ + l];
        }
        lds[rl][ll] = v;
    }
    __syncthreads();
    #pragma unroll
    for (int i = 0; i < 16; ++i) {
        const int e  = i * 256 + tid;
        const int ll = e >> 6, rl = e & 63;
        params[(size_t)(lt * 64 + ll) * NROWS + rt * 64 + rl] = lds[rl][ll];
    }
}

// LDS h buffer: [parity][link 0..3][b 0..31][k 0..63] fp16, XOR-swizzled rows
__device__ __forceinline__ int h_byte(int p, int w, int b, int k) {
    int byte = ((((p * 4 + w) * 32 + b) * 64) + k) * 2;
    return byte ^ ((b & 7) << 4);
}

// ---------------------------------------------------------------------------
// Persistent GRU: 256 blocks (1/CU), wave w owns link 4c+w for all T steps.
// Weights in registers; interior neighbors via LDS; chunk-edge h via
// coherent-point (agent-scope atomic) u64 stores/loads -- NO cache fences.
// gh layout: [parity][chunk][side][b][k] fp16, side 0 = link 4c, 1 = 4c+3.
// ---------------------------------------------------------------------------
__global__ __launch_bounds__(256, 1) void gru_persist(
    const float* __restrict__ w_rh, const float* __restrict__ w_uh,
    const float* __restrict__ w_nh,
    const float* __restrict__ w_ri, const float* __restrict__ w_ui,
    const float* __restrict__ w_ni,
    const float* __restrict__ att,  const float* __restrict__ params,
    const float* __restrict__ w_fc, const float* __restrict__ b_fc,
    _Float16* __restrict__ gh, int* __restrict__ flags,
    float* __restrict__ out)
{
    const int c    = chunk_of_block(blockIdx.x);
    const int tid  = threadIdx.x;
    const int w    = tid >> 6, lane = tid & 63;
    const int n    = lane & 15, kq = lane >> 4;
    const int l    = c * 4 + w;

    __shared__ __align__(16) _Float16 hbuf[2 * 4 * 32 * 64];  // 32 KB
    __shared__ __align__(16) float    xs[4][1536];            // 24 KB

    // ---- stage this link's x into LDS, coalesced
    const float* prow = params + (size_t)l * NROWS;
    {
        const float4* src = (const float4*)prow;
        float4* dst = (float4*)xs[w];
        #pragma unroll
        for (int i = 0; i < 6; ++i) dst[lane + i * 64] = src[lane + i * 64];
    }

    // ---- per-lane persistent constants
    f16x8 bw[3][4][2];   // B fragments [gate][ntile][ks]
    {
        const float* wh[3] = { w_rh, w_uh, w_nh };
        #pragma unroll
        for (int g = 0; g < 3; ++g)
            #pragma unroll
            for (int nt = 0; nt < 4; ++nt)
                #pragma unroll
                for (int ks = 0; ks < 2; ++ks) {
                    f16x8 v;
                    #pragma unroll
                    for (int j = 0; j < 8; ++j)
                        v[j] = (_Float16)wh[g][(size_t)l * 4096
                                 + (size_t)(ks * 32 + kq * 8 + j) * 64 + nt * 16 + n];
                    bw[g][nt][ks] = v;
                }
    }
    float wxv[3][4][4];  // [gate][f][ntile]
    {
        const float* wxp[3] = { w_ri, w_ui, w_ni };
        #pragma unroll
        for (int g = 0; g < 3; ++g)
            #pragma unroll
            for (int f = 0; f < F_; ++f)
                #pragma unroll
                for (int nt = 0; nt < 4; ++nt)
                    wxv[g][f][nt] = wxp[g][(size_t)l * 256 + f * 64 + nt * 16 + n];
    }
    float brv[4], bzv[4], bnhv[4], bniv[4], wfcv[4];
    #pragma unroll
    for (int nt = 0; nt < 4; ++nt) {
        const int ko = nt * 16 + n;
        brv[nt]  = prow[1536 + 0 * 64 + ko] + prow[1536 + 1 * 64 + ko];
        bzv[nt]  = prow[1536 + 2 * 64 + ko] + prow[1536 + 3 * 64 + ko];
        bnhv[nt] = prow[1536 + 4 * 64 + ko];
        bniv[nt] = prow[1536 + 5 * 64 + ko];
        wfcv[nt] = w_fc[(size_t)l * H_ + ko];
    }
    const float a_c = att[(size_t)l * L_ + l];
    const float a_l = (l > 0)      ? att[(size_t)l * L_ + l - 1] : 0.0f;
    const float a_r = (l < L_ - 1) ? att[(size_t)l * L_ + l + 1] : 0.0f;

    __syncthreads();   // xs ready

    float hv[2][4][4] = {};   // [mt][nt][r]

    #pragma unroll 1
    for (int t = 0; t < T_; ++t) {
        f32x4 acc[3][2][4] = {};   // [gate][mt][nt]
        if (t > 0) {
            // wait for neighbor chunks' step t-1 publication (acquire)
            if (c > 0 && tid == 0)
                while (__hip_atomic_load(&flags[c - 1], __ATOMIC_ACQUIRE,
                                         __HIP_MEMORY_SCOPE_AGENT) < t)
                    __builtin_amdgcn_s_sleep(2);
            if (c < NCH - 1 && tid == 255)
                while (__hip_atomic_load(&flags[c + 1], __ATOMIC_ACQUIRE,
                                         __HIP_MEMORY_SCOPE_AGENT) < t)
                    __builtin_amdgcn_s_sleep(2);
            __syncthreads();

            const int p = (t - 1) & 1;
            const char* hb = (const char*)hbuf;
            f16x8 af[2][2];
            #pragma unroll
            for (int mt = 0; mt < 2; ++mt) {
                #pragma unroll
                for (int ks = 0; ks < 2; ++ks) {
                    const int b  = mt * 16 + n;
                    const int k0 = ks * 32 + kq * 8;
                    const f16x8 hs = *(const f16x8*)(hb + h_byte(p, w, b, k0));
                    f16x8 hl, hr;
                    if (w > 0) {
                        hl = *(const f16x8*)(hb + h_byte(p, w - 1, b, k0));
                    } else if (c > 0) {
                        const u64* s64 = (const u64*)(gh +
                            ((((size_t)p * NCH + (c - 1)) * 2 + 1) * 2048));
                        union { u64 uu[2]; f16x8 v; } cv;
                        cv.uu[0] = __hip_atomic_load(s64 + b * 16 + (k0 >> 2),
                                     __ATOMIC_RELAXED, __HIP_MEMORY_SCOPE_AGENT);
                        cv.uu[1] = __hip_atomic_load(s64 + b * 16 + (k0 >> 2) + 1,
                                     __ATOMIC_RELAXED, __HIP_MEMORY_SCOPE_AGENT);
                        hl = cv.v;
                    } else {
                        hl = hs;   // a_l == 0
                    }
                    if (w < 3) {
                        hr = *(const f16x8*)(hb + h_byte(p, w + 1, b, k0));
                    } else if (c < NCH - 1) {
                        const u64* s64 = (const u64*)(gh +
                            ((((size_t)p * NCH + (c + 1)) * 2 + 0) * 2048));
                        union { u64 uu[2]; f16x8 v; } cv;
                        cv.uu[0] = __hip_atomic_load(s64 + b * 16 + (k0 >> 2),
                                     __ATOMIC_RELAXED, __HIP_MEMORY_SCOPE_AGENT);
                        cv.uu[1] = __hip_atomic_load(s64 + b * 16 + (k0 >> 2) + 1,
                                     __ATOMIC_RELAXED, __HIP_MEMORY_SCOPE_AGENT);
                        hr = cv.v;
                    } else {
                        hr = hs;   // a_r == 0
                    }
                    f16x8 a;
                    #pragma unroll
                    for (int j = 0; j < 8; ++j)
                        a[j] = (_Float16)(a_c * (float)hs[j] + a_l * (float)hl[j]
                                        + a_r * (float)hr[j]);
                    af[mt][ks] = a;
                }
            }
            #pragma unroll
            for (int g = 0; g < 3; ++g)
                #pragma unroll
                for (int nt = 0; nt < 4; ++nt)
                    #pragma unroll
                    for (int ks = 0; ks < 2; ++ks)
                        #pragma unroll
                        for (int mt = 0; mt < 2; ++mt)
                            acc[g][mt][nt] = __builtin_amdgcn_mfma_f32_16x16x32_f16(
                                af[mt][ks], bw[g][nt][ks], acc[g][mt][nt], 0, 0, 0);
        }

        // ---- epilogue (f32)
        #pragma unroll
        for (int mt = 0; mt < 2; ++mt) {
            #pragma unroll
            for (int r = 0; r < 4; ++r) {
                const int b = mt * 16 + kq * 4 + r;
                const float4 xb = *(const float4*)&xs[w][b * 48 + t * 4];
                #pragma unroll
                for (int nt = 0; nt < 4; ++nt) {
                    const float xr = xb.x*wxv[0][0][nt] + xb.y*wxv[0][1][nt]
                                   + xb.z*wxv[0][2][nt] + xb.w*wxv[0][3][nt];
                    const float xz = xb.x*wxv[1][0][nt] + xb.y*wxv[1][1][nt]
                                   + xb.z*wxv[1][2][nt] + xb.w*wxv[1][3][nt];
                    const float xn = xb.x*wxv[2][0][nt] + xb.y*wxv[2][1][nt]
                                   + xb.z*wxv[2][2][nt] + xb.w*wxv[2][3][nt];
                    const float pre_r = acc[0][mt][nt][r] + brv[nt] + xr;
                    const float pre_z = acc[1][mt][nt][r] + bzv[nt] + xz;
                    const float rg = 1.0f / (1.0f + __expf(-pre_r));
                    const float zg = 1.0f / (1.0f + __expf(-pre_z));
                    float npre = xn + bniv[nt] + rg * (acc[2][mt][nt][r] + bnhv[nt]);
                    npre = fminf(fmaxf(npre, -15.0f), 15.0f);
                    const float e2 = __expf(2.0f * npre);
                    const float nn = (e2 - 1.0f) / (e2 + 1.0f);
                    hv[mt][nt][r] = (1.0f - zg) * nn + zg * hv[mt][nt][r];
                }
            }
        }

        if (t < T_ - 1) {
            const int q = t & 1;
            char* hb = (char*)hbuf;
            #pragma unroll
            for (int mt = 0; mt < 2; ++mt)
                #pragma unroll
                for (int nt = 0; nt < 4; ++nt)
                    #pragma unroll
                    for (int r = 0; r < 4; ++r) {
                        const int b = mt * 16 + kq * 4 + r;
                        const int k = nt * 16 + n;
                        *(_Float16*)(hb + h_byte(q, w, b, k)) = (_Float16)hv[mt][nt][r];
                    }
            // edge waves re-read own 4 KB from LDS (in-wave order) and push to
            // the coherent point as u64 atomics -- no fences anywhere.
            if ((w == 0 && c > 0) || (w == 3 && c < NCH - 1)) {
                const int side = (w == 0) ? 0 : 1;
                u64* ge64 = (u64*)(gh + (((size_t)q * NCH + c) * 2 + side) * 2048);
                #pragma unroll
                for (int i = 0; i < 8; ++i) {
                    const int idx = lane + i * 64;     // u64 index 0..511
                    const int b = idx >> 4, kk = idx & 15;
                    const u64 v = *(const u64*)(hb + h_byte(q, w, b, kk * 4));
                    __hip_atomic_store(ge64 + idx, v, __ATOMIC_RELAXED,
                                       __HIP_MEMORY_SCOPE_AGENT);
                }
            }
            __syncthreads();   // drains every wave's LDS + atomic stores
            if (tid == 0)
                __hip_atomic_store(&flags[c], t + 1, __ATOMIC_RELEASE,
                                   __HIP_MEMORY_SCOPE_AGENT);
        } else {
            // FC head: out[b][0][l] = sum_k h[b][k]*w_fc[l][k] + b_fc[l]
            #pragma unroll
            for (int mt = 0; mt < 2; ++mt)
                #pragma unroll
                for (int r = 0; r < 4; ++r) {
                    float s = hv[mt][0][r] * wfcv[0] + hv[mt][1][r] * wfcv[1]
                            + hv[mt][2][r] * wfcv[2] + hv[mt][3][r] * wfcv[3];
                    s += __shfl_xor(s, 1, 64);
                    s += __shfl_xor(s, 2, 64);
                    s += __shfl_xor(s, 4, 64);
                    s += __shfl_xor(s, 8, 64);
                    if (n == 0)
                        out[(size_t)(mt * 16 + kq * 4 + r) * L_ + l] = s + b_fc[l];
                }
        }
    }
}

extern "C" void kernel_launch(void* const* d_in, const int* in_sizes, int n_in,
                              void* d_out, int out_size, void* d_ws, size_t ws_size,
                              hipStream_t stream) {
    const float* x    = (const float*)d_in[0];
    const float* att  = (const float*)d_in[1];
    const float* w_rh = (const float*)d_in[2];
    const float* b_rh = (const float*)d_in[3];
    const float* w_ri = (const float*)d_in[4];
    const float* b_ri = (const float*)d_in[5];
    const float* w_uh = (const float*)d_in[6];
    const float* b_uh = (const float*)d_in[7];
    const float* w_ui = (const float*)d_in[8];
    const float* b_ui = (const float*)d_in[9];
    const float* w_nh = (const float*)d_in[10];
    const float* b_nh = (const float*)d_in[11];
    const float* w_ni = (const float*)d_in[12];
    const float* b_ni = (const float*)d_in[13];
    const float* w_fc = (const float*)d_in[14];
    const float* b_fc = (const float*)d_in[15];
    float* out = (float*)d_out;

    char* ws = (char*)d_ws;
    float*    params = (float*)ws;                    // 7.9 MB
    _Float16* gh     = (_Float16*)(ws + (8u << 20));  // 4 MB edge halos
    int*      flags  = (int*)(ws + (13u << 20));      // 1 KB

    prep<<<480, 256, 0, stream>>>(x, b_rh, b_ri, b_uh, b_ui, b_nh, b_ni,
                                  params, flags);

    void* args[] = {
        (void*)&w_rh, (void*)&w_uh, (void*)&w_nh,
        (void*)&w_ri, (void*)&w_ui, (void*)&w_ni,
        (void*)&att,  (void*)&params, (void*)&w_fc, (void*)&b_fc,
        (void*)&gh,   (void*)&flags,  (void*)&out,
    };
    hipError_t e = hipLaunchCooperativeKernel((const void*)gru_persist,
                                              dim3(NCH), dim3(256), args, 0, stream);
    if (e != hipSuccess) {
        // 256 blocks at <=1 block/CU on 256 CUs: co-resident regardless.
        gru_persist<<<NCH, 256, 0, stream>>>(w_rh, w_uh, w_nh, w_ri, w_ui, w_ni,
                                             att, params, w_fc, b_fc,
                                             gh, flags, out);
    }
}

// Round 6
// 196.375 us; speedup vs baseline: 2.6055x; 1.1492x over previous
//
#include <hip/hip_runtime.h>

#define B_ 32
#define T_ 12
#define F_ 4
#define L_ 1024
#define H_ 64
#define NROWS 1920   // 1536 x rows + 6*64 bias rows
#define NCH 256      // chunks (blocks); 4 links per chunk

typedef _Float16 f16x8 __attribute__((ext_vector_type(8)));
typedef float f32x4 __attribute__((ext_vector_type(4)));
typedef unsigned long long u64;

// XCD-chunked swizzle: XCD x owns chunks [32x, 32x+32) = links [128x, 128x+128)
__device__ __forceinline__ int chunk_of_block(int bid) {
    return ((bid & 7) << 5) + (bid >> 3);
}

// ---------------------------------------------------------------------------
// Prep: transpose x [1536 rows][L] and 6 bias arrays [64 rows][L] into
// params[l][NROWS], zero the flags.
// ---------------------------------------------------------------------------
__global__ __launch_bounds__(256) void prep(
    const float* __restrict__ x,
    const float* __restrict__ b_rh, const float* __restrict__ b_ri,
    const float* __restrict__ b_uh, const float* __restrict__ b_ui,
    const float* __restrict__ b_nh, const float* __restrict__ b_ni,
    float* __restrict__ params, int* __restrict__ flags)
{
    const int tid = threadIdx.x;
    const int rt  = blockIdx.x >> 4;   // 30 row tiles
    const int lt  = blockIdx.x & 15;   // 16 link tiles
    __shared__ float lds[64][65];

    if (blockIdx.x == 0 && tid < NCH)
        __hip_atomic_store(&flags[tid], 0, __ATOMIC_RELAXED, __HIP_MEMORY_SCOPE_AGENT);

    #pragma unroll
    for (int i = 0; i < 16; ++i) {
        const int e  = i * 256 + tid;
        const int rl = e >> 6, ll = e & 63;
        const int r  = rt * 64 + rl, l = lt * 64 + ll;
        float v;
        if (r < 1536) {
            v = x[(size_t)r * L_ + l];
        } else {
            const int rb = r - 1536;
            const int g  = rb >> 6;
            const float* bp = (g == 0) ? b_rh : (g == 1) ? b_ri : (g == 2) ? b_uh
                            : (g == 3) ? b_ui : (g == 4) ? b_nh : b_ni;
            v = bp[(size_t)(rb & 63) * L_ + l];
        }
        lds[rl][ll] = v;
    }
    __syncthreads();
    #pragma unroll
    for (int i = 0; i < 16; ++i) {
        const int e  = i * 256 + tid;
        const int ll = e >> 6, rl = e & 63;
        params[(size_t)(lt * 64 + ll) * NROWS + rt * 64 + rl] = lds[rl][ll];
    }
}

// ---------------------------------------------------------------------------
// Prep_w: gather the three HxH gate matrices into per-lane fragment order:
// Wpk[l][lane][f] (f16x8), f = g*8 + nt*2 + ks -- so the persistent kernel's
// prologue is 24 coalesced 16B loads per lane.
// ---------------------------------------------------------------------------
__global__ __launch_bounds__(256) void prep_w(
    const float* __restrict__ w_rh, const float* __restrict__ w_uh,
    const float* __restrict__ w_nh, _Float16* __restrict__ Wpk)
{
    const int l   = blockIdx.x;
    const int tid = threadIdx.x;
    const float* wh[3] = { w_rh, w_uh, w_nh };
    #pragma unroll
    for (int i = 0; i < 6; ++i) {
        const int phi = i * 256 + tid;        // 0..1535
        const int m = phi & 63, f = phi >> 6; // lane, frag
        const int g = f >> 3, rem = f & 7, nt = rem >> 1, ks = rem & 1;
        const int n = m & 15, kq = m >> 4;
        f16x8 v;
        #pragma unroll
        for (int j = 0; j < 8; ++j)
            v[j] = (_Float16)wh[g][(size_t)l * 4096
                     + (size_t)(ks * 32 + kq * 8 + j) * 64 + nt * 16 + n];
        *(f16x8*)(Wpk + (((size_t)l * 64 + m) * 24 + f) * 8) = v;
    }
}

// LDS h buffer: [parity][link 0..3][b 0..31][k 0..63] fp16, XOR-swizzled rows
__device__ __forceinline__ int h_byte(int p, int w, int b, int k) {
    int byte = ((((p * 4 + w) * 32 + b) * 64) + k) * 2;
    return byte ^ ((b & 7) << 4);
}

// ---------------------------------------------------------------------------
// Persistent GRU: 256 blocks (1/CU), wave w owns link 4c+w for all T steps.
// Weights in registers (coalesced fp16 prologue from Wpk); interior neighbors
// via LDS; chunk-edge h via coherent-point (agent-scope atomic) u64
// stores/loads; flags polled RELAXED (no cache maintenance per poll).
// ---------------------------------------------------------------------------
__global__ __launch_bounds__(256, 1) void gru_persist(
    const _Float16* __restrict__ Wpk,
    const float* __restrict__ w_ri, const float* __restrict__ w_ui,
    const float* __restrict__ w_ni,
    const float* __restrict__ att,  const float* __restrict__ params,
    const float* __restrict__ w_fc, const float* __restrict__ b_fc,
    _Float16* __restrict__ gh, int* __restrict__ flags,
    float* __restrict__ out)
{
    const int c    = chunk_of_block(blockIdx.x);
    const int tid  = threadIdx.x;
    const int w    = tid >> 6, lane = tid & 63;
    const int n    = lane & 15, kq = lane >> 4;
    const int l    = c * 4 + w;

    __shared__ __align__(16) _Float16 hbuf[2 * 4 * 32 * 64];  // 32 KB
    __shared__ __align__(16) float    xs[4][1536];            // 24 KB

    // ---- stage this link's x into LDS, coalesced
    const float* prow = params + (size_t)l * NROWS;
    {
        const float4* src = (const float4*)prow;
        float4* dst = (float4*)xs[w];
        #pragma unroll
        for (int i = 0; i < 6; ++i) dst[lane + i * 64] = src[lane + i * 64];
    }

    // ---- per-lane persistent constants (all coalesced now)
    f16x8 bw[3][4][2];   // B fragments [gate][ntile][ks]
    {
        const f16x8* wp = (const f16x8*)(Wpk + ((size_t)l * 64 + lane) * 24 * 8);
        #pragma unroll
        for (int g = 0; g < 3; ++g)
            #pragma unroll
            for (int nt = 0; nt < 4; ++nt)
                #pragma unroll
                for (int ks = 0; ks < 2; ++ks)
                    bw[g][nt][ks] = wp[g * 8 + nt * 2 + ks];
    }
    float wxv[3][4][4];  // [gate][f][ntile]
    {
        const float* wxp[3] = { w_ri, w_ui, w_ni };
        #pragma unroll
        for (int g = 0; g < 3; ++g)
            #pragma unroll
            for (int f = 0; f < F_; ++f)
                #pragma unroll
                for (int nt = 0; nt < 4; ++nt)
                    wxv[g][f][nt] = wxp[g][(size_t)l * 256 + f * 64 + nt * 16 + n];
    }
    float brv[4], bzv[4], bnhv[4], bniv[4], wfcv[4];
    #pragma unroll
    for (int nt = 0; nt < 4; ++nt) {
        const int ko = nt * 16 + n;
        brv[nt]  = prow[1536 + 0 * 64 + ko] + prow[1536 + 1 * 64 + ko];
        bzv[nt]  = prow[1536 + 2 * 64 + ko] + prow[1536 + 3 * 64 + ko];
        bnhv[nt] = prow[1536 + 4 * 64 + ko];
        bniv[nt] = prow[1536 + 5 * 64 + ko];
        wfcv[nt] = w_fc[(size_t)l * H_ + ko];
    }
    const float a_c = att[(size_t)l * L_ + l];
    const float a_l = (l > 0)      ? att[(size_t)l * L_ + l - 1] : 0.0f;
    const float a_r = (l < L_ - 1) ? att[(size_t)l * L_ + l + 1] : 0.0f;

    __syncthreads();   // xs ready

    float hv[2][4][4] = {};   // [mt][nt][r]

    #pragma unroll 1
    for (int t = 0; t < T_; ++t) {
        f32x4 acc[3][2][4] = {};   // [gate][mt][nt]
        if (t > 0) {
            // wait for neighbor chunks' step t-1 publication. RELAXED polls:
            // flags+halos are coherent-point atomics; in-order wave execution
            // orders the control-dependent halo loads after the flag load.
            if (c > 0 && tid == 0)
                while (__hip_atomic_load(&flags[c - 1], __ATOMIC_RELAXED,
                                         __HIP_MEMORY_SCOPE_AGENT) < t)
                    __builtin_amdgcn_s_sleep(2);
            if (c < NCH - 1 && tid == 255)
                while (__hip_atomic_load(&flags[c + 1], __ATOMIC_RELAXED,
                                         __HIP_MEMORY_SCOPE_AGENT) < t)
                    __builtin_amdgcn_s_sleep(2);
            __syncthreads();

            const int p = (t - 1) & 1;
            const char* hb = (const char*)hbuf;
            f16x8 af[2][2];
            #pragma unroll
            for (int mt = 0; mt < 2; ++mt) {
                #pragma unroll
                for (int ks = 0; ks < 2; ++ks) {
                    const int b  = mt * 16 + n;
                    const int k0 = ks * 32 + kq * 8;
                    const f16x8 hs = *(const f16x8*)(hb + h_byte(p, w, b, k0));
                    f16x8 hl, hr;
                    if (w > 0) {
                        hl = *(const f16x8*)(hb + h_byte(p, w - 1, b, k0));
                    } else if (c > 0) {
                        const u64* s64 = (const u64*)(gh +
                            ((((size_t)p * NCH + (c - 1)) * 2 + 1) * 2048));
                        union { u64 uu[2]; f16x8 v; } cv;
                        cv.uu[0] = __hip_atomic_load(s64 + b * 16 + (k0 >> 2),
                                     __ATOMIC_RELAXED, __HIP_MEMORY_SCOPE_AGENT);
                        cv.uu[1] = __hip_atomic_load(s64 + b * 16 + (k0 >> 2) + 1,
                                     __ATOMIC_RELAXED, __HIP_MEMORY_SCOPE_AGENT);
                        hl = cv.v;
                    } else {
                        hl = hs;   // a_l == 0
                    }
                    if (w < 3) {
                        hr = *(const f16x8*)(hb + h_byte(p, w + 1, b, k0));
                    } else if (c < NCH - 1) {
                        const u64* s64 = (const u64*)(gh +
                            ((((size_t)p * NCH + (c + 1)) * 2 + 0) * 2048));
                        union { u64 uu[2]; f16x8 v; } cv;
                        cv.uu[0] = __hip_atomic_load(s64 + b * 16 + (k0 >> 2),
                                     __ATOMIC_RELAXED, __HIP_MEMORY_SCOPE_AGENT);
                        cv.uu[1] = __hip_atomic_load(s64 + b * 16 + (k0 >> 2) + 1,
                                     __ATOMIC_RELAXED, __HIP_MEMORY_SCOPE_AGENT);
                        hr = cv.v;
                    } else {
                        hr = hs;   // a_r == 0
                    }
                    f16x8 a;
                    #pragma unroll
                    for (int j = 0; j < 8; ++j)
                        a[j] = (_Float16)(a_c * (float)hs[j] + a_l * (float)hl[j]
                                        + a_r * (float)hr[j]);
                    af[mt][ks] = a;
                }
            }
            #pragma unroll
            for (int g = 0; g < 3; ++g)
                #pragma unroll
                for (int nt = 0; nt < 4; ++nt)
                    #pragma unroll
                    for (int ks = 0; ks < 2; ++ks)
                        #pragma unroll
                        for (int mt = 0; mt < 2; ++mt)
                            acc[g][mt][nt] = __builtin_amdgcn_mfma_f32_16x16x32_f16(
                                af[mt][ks], bw[g][nt][ks], acc[g][mt][nt], 0, 0, 0);
        }

        // ---- epilogue (f32)
        #pragma unroll
        for (int mt = 0; mt < 2; ++mt) {
            #pragma unroll
            for (int r = 0; r < 4; ++r) {
                const int b = mt * 16 + kq * 4 + r;
                const float4 xb = *(const float4*)&xs[w][b * 48 + t * 4];
                #pragma unroll
                for (int nt = 0; nt < 4; ++nt) {
                    const float xr = xb.x*wxv[0][0][nt] + xb.y*wxv[0][1][nt]
                                   + xb.z*wxv[0][2][nt] + xb.w*wxv[0][3][nt];
                    const float xz = xb.x*wxv[1][0][nt] + xb.y*wxv[1][1][nt]
                                   + xb.z*wxv[1][2][nt] + xb.w*wxv[1][3][nt];
                    const float xn = xb.x*wxv[2][0][nt] + xb.y*wxv[2][1][nt]
                                   + xb.z*wxv[2][2][nt] + xb.w*wxv[2][3][nt];
                    const float pre_r = acc[0][mt][nt][r] + brv[nt] + xr;
                    const float pre_z = acc[1][mt][nt][r] + bzv[nt] + xz;
                    const float rg = 1.0f / (1.0f + __expf(-pre_r));
                    const float zg = 1.0f / (1.0f + __expf(-pre_z));
                    float npre = xn + bniv[nt] + rg * (acc[2][mt][nt][r] + bnhv[nt]);
                    npre = fminf(fmaxf(npre, -15.0f), 15.0f);
                    const float e2 = __expf(2.0f * npre);
                    const float nn = (e2 - 1.0f) / (e2 + 1.0f);
                    hv[mt][nt][r] = (1.0f - zg) * nn + zg * hv[mt][nt][r];
                }
            }
        }

        if (t < T_ - 1) {
            const int q = t & 1;
            char* hb = (char*)hbuf;
            #pragma unroll
            for (int mt = 0; mt < 2; ++mt)
                #pragma unroll
                for (int nt = 0; nt < 4; ++nt)
                    #pragma unroll
                    for (int r = 0; r < 4; ++r) {
                        const int b = mt * 16 + kq * 4 + r;
                        const int k = nt * 16 + n;
                        *(_Float16*)(hb + h_byte(q, w, b, k)) = (_Float16)hv[mt][nt][r];
                    }
            // edge waves push their 4 KB to the coherent point as u64 atomics
            if ((w == 0 && c > 0) || (w == 3 && c < NCH - 1)) {
                const int side = (w == 0) ? 0 : 1;
                u64* ge64 = (u64*)(gh + (((size_t)q * NCH + c) * 2 + side) * 2048);
                #pragma unroll
                for (int i = 0; i < 8; ++i) {
                    const int idx = lane + i * 64;     // u64 index 0..511
                    const int b = idx >> 4, kk = idx & 15;
                    const u64 v = *(const u64*)(hb + h_byte(q, w, b, kk * 4));
                    __hip_atomic_store(ge64 + idx, v, __ATOMIC_RELAXED,
                                       __HIP_MEMORY_SCOPE_AGENT);
                }
            }
            __syncthreads();   // compiler drains vmcnt(0) per wave before barrier
            if (tid == 0)
                __hip_atomic_store(&flags[c], t + 1, __ATOMIC_RELEASE,
                                   __HIP_MEMORY_SCOPE_AGENT);
        } else {
            // FC head: out[b][0][l] = sum_k h[b][k]*w_fc[l][k] + b_fc[l]
            #pragma unroll
            for (int mt = 0; mt < 2; ++mt)
                #pragma unroll
                for (int r = 0; r < 4; ++r) {
                    float s = hv[mt][0][r] * wfcv[0] + hv[mt][1][r] * wfcv[1]
                            + hv[mt][2][r] * wfcv[2] + hv[mt][3][r] * wfcv[3];
                    s += __shfl_xor(s, 1, 64);
                    s += __shfl_xor(s, 2, 64);
                    s += __shfl_xor(s, 4, 64);
                    s += __shfl_xor(s, 8, 64);
                    if (n == 0)
                        out[(size_t)(mt * 16 + kq * 4 + r) * L_ + l] = s + b_fc[l];
                }
        }
    }
}

extern "C" void kernel_launch(void* const* d_in, const int* in_sizes, int n_in,
                              void* d_out, int out_size, void* d_ws, size_t ws_size,
                              hipStream_t stream) {
    const float* x    = (const float*)d_in[0];
    const float* att  = (const float*)d_in[1];
    const float* w_rh = (const float*)d_in[2];
    const float* b_rh = (const float*)d_in[3];
    const float* w_ri = (const float*)d_in[4];
    const float* b_ri = (const float*)d_in[5];
    const float* w_uh = (const float*)d_in[6];
    const float* b_uh = (const float*)d_in[7];
    const float* w_ui = (const float*)d_in[8];
    const float* b_ui = (const float*)d_in[9];
    const float* w_nh = (const float*)d_in[10];
    const float* b_nh = (const float*)d_in[11];
    const float* w_ni = (const float*)d_in[12];
    const float* b_ni = (const float*)d_in[13];
    const float* w_fc = (const float*)d_in[14];
    const float* b_fc = (const float*)d_in[15];
    float* out = (float*)d_out;

    char* ws = (char*)d_ws;
    float*    params = (float*)ws;                     // 7.9 MB
    _Float16* gh     = (_Float16*)(ws + (8u << 20));   // 4 MB edge halos
    int*      flags  = (int*)(ws + (13u << 20));       // 1 KB
    _Float16* Wpk    = (_Float16*)(ws + (16u << 20));  // 24 MB packed weights

    prep<<<480, 256, 0, stream>>>(x, b_rh, b_ri, b_uh, b_ui, b_nh, b_ni,
                                  params, flags);
    prep_w<<<L_, 256, 0, stream>>>(w_rh, w_uh, w_nh, Wpk);

    void* args[] = {
        (void*)&Wpk,
        (void*)&w_ri, (void*)&w_ui, (void*)&w_ni,
        (void*)&att,  (void*)&params, (void*)&w_fc, (void*)&b_fc,
        (void*)&gh,   (void*)&flags,  (void*)&out,
    };
    hipError_t e = hipLaunchCooperativeKernel((const void*)gru_persist,
                                              dim3(NCH), dim3(256), args, 0, stream);
    if (e != hipSuccess) {
        // 256 blocks at <=1 block/CU on 256 CUs: co-resident regardless.
        gru_persist<<<NCH, 256, 0, stream>>>(Wpk, w_ri, w_ui, w_ni,
                                             att, params, w_fc, b_fc,
                                             gh, flags, out);
    }
}